// Round 1
// baseline (211.338 us; speedup 1.0000x reference)
//
#include <hip/hip_runtime.h>
#include <hip/hip_bf16.h>
#include <stdint.h>

#define N_   64
#define L_   1024
#define D_   512
#define S_   127
#define OUT_ 300
#define NT_  20            // 20 col-tiles of 16 -> 320 padded cols
#define OUTP (NT_*16)      // 320
#define EPS_ 1e-5f
#define M_TOTAL (N_*S_)    // 8128
#define BM 16
#define BK 64
#define NBLK (M_TOTAL/BM)  // 508 (exact)
#define ASTR 72            // LDS row stride (bf16 elems), 144B: 16B-aligned + depads banks
#define BSTR 72
#define HSTR 320           // epilogue h stride (floats)

typedef __attribute__((ext_vector_type(4))) float  float4v;
typedef __attribute__((ext_vector_type(8))) __bf16 bf16x8;
typedef __attribute__((ext_vector_type(4))) __bf16 bf16x4;

// --- w_lin f32 -> bf16, padded to 320 rows (rows >=300 are zero) ---
__global__ void conv_w_kernel(const float* __restrict__ w, __bf16* __restrict__ wbf) {
    int idx = blockIdx.x * 256 + threadIdx.x;          // exactly 320*512 threads
    int o = idx >> 9, d = idx & (D_ - 1);
    float v = (o < OUT_) ? w[o * D_ + d] : 0.0f;
    wbf[idx] = (__bf16)v;
}

// --- use = t1[:,0,:] ---
__global__ void use_copy_kernel(const float* __restrict__ t1, float* __restrict__ ou) {
    int idx = blockIdx.x * 256 + threadIdx.x;          // 8192 threads, float4 each
    int n = idx >> 7, dg = idx & 127;
    float4v v = *(const float4v*)(t1 + (size_t)n * L_ * D_ + dg * 4);
    *(float4v*)(ou + n * D_ + dg * 4) = v;
}

// --- fused: span-means -> bf16 MFMA GEMM (+bias) -> LayerNorm ---
__global__ __launch_bounds__(256) void enc_main(
    const float* __restrict__ t1, const int* __restrict__ wseq,
    const __bf16* __restrict__ wbf, const float* __restrict__ b_lin,
    const float* __restrict__ gamma, const float* __restrict__ beta,
    float* __restrict__ out)
{
    __shared__ __align__(16) char smem[BM*ASTR*2 + OUTP*BSTR*2];  // 48384 B
    __bf16* Alds = (__bf16*)smem;                    // [16][72]
    __bf16* Blds = (__bf16*)(smem + BM*ASTR*2);      // [320][72]
    float*  hlds = (float*)smem;                     // [16][320], aliased after final barrier

    const int tid  = threadIdx.x;
    const int blk  = blockIdx.x;
    const int lane = tid & 63;
    const int wave = tid >> 6;
    const int quad = lane >> 4;
    const int ln16 = lane & 15;

    // A-staging role: one (row, 4-wide k-group) per thread
    const int ar  = tid >> 4;        // 0..15
    const int akg = tid & 15;        // 0..15
    const int mg  = blk * BM + ar;   // global (n,s) row, < 8128
    const int nn  = mg / S_;
    const int st  = min(wseq[mg * 2 + 0], L_ - 3);   // min(start, li-1)
    const int en  = min(wseq[mg * 2 + 1], L_ - 2);   // min(end, li)
    const int cnt = en - st;
    const float inv_cnt = 1.0f / (float)cnt;
    const float* abase = t1 + ((size_t)nn * L_ + 1 + st) * D_ + akg * 4;

    float4v acc[5];
    #pragma unroll
    for (int i = 0; i < 5; ++i) acc[i] = float4v{0.f, 0.f, 0.f, 0.f};

    const int t0 = wave * 5;   // this wave's first col-tile (uniform 5 tiles/wave)

    for (int kt = 0; kt < D_ / BK; ++kt) {
        const int k0 = kt * BK;

        // ---- stage A: span mean of t1 rows, f32 accumulate, bf16 store
        float4v s4 = {0.f, 0.f, 0.f, 0.f};
        if (cnt == 8) {                    // fast path (always true for this data)
            #pragma unroll
            for (int j = 0; j < 8; ++j)
                s4 += *(const float4v*)(abase + k0 + j * D_);
        } else {
            for (int j = 0; j < cnt; ++j)
                s4 += *(const float4v*)(abase + k0 + j * D_);
        }
        s4 *= inv_cnt;
        bf16x4 a4;
        a4[0] = (__bf16)s4[0]; a4[1] = (__bf16)s4[1];
        a4[2] = (__bf16)s4[2]; a4[3] = (__bf16)s4[3];
        *(bf16x4*)(Alds + ar * ASTR + akg * 4) = a4;

        // ---- stage B: 320 rows x 64 k of bf16 weights, 16B vector moves
        #pragma unroll
        for (int it = 0; it < 10; ++it) {
            int idx = tid + it * 256;            // < 2560 = 320*8 groups
            int row = idx >> 3, kg = idx & 7;
            bf16x8 v = *(const bf16x8*)(wbf + row * D_ + k0 + kg * 8);
            *(bf16x8*)(Blds + row * BSTR + kg * 8) = v;
        }
        __syncthreads();

        // ---- MFMA: 2 k-steps x 5 col-tiles
        #pragma unroll
        for (int ks = 0; ks < 2; ++ks) {
            const int kk = ks * 32;
            bf16x8 af = *(const bf16x8*)(Alds + ln16 * ASTR + kk + quad * 8);
            #pragma unroll
            for (int i = 0; i < 5; ++i) {
                const int orow = (t0 + i) * 16 + ln16;
                bf16x8 bfr = *(const bf16x8*)(Blds + orow * BSTR + kk + quad * 8);
                acc[i] = __builtin_amdgcn_mfma_f32_16x16x32_bf16(af, bfr, acc[i], 0, 0, 0);
            }
        }
        __syncthreads();
    }

    // ---- epilogue: h = acc + b_lin into LDS (C-layout: row = quad*4+reg, col = lane&15)
    #pragma unroll
    for (int i = 0; i < 5; ++i) {
        const int col = (t0 + i) * 16 + ln16;
        const float bl = (col < OUT_) ? b_lin[col] : 0.0f;
        #pragma unroll
        for (int r = 0; r < 4; ++r)
            hlds[(quad * 4 + r) * HSTR + col] = acc[i][r] + bl;
    }
    __syncthreads();

    // ---- LayerNorm over 300 cols; 16 threads per row, shfl-reduce within 16-lane group
    const int r  = tid >> 4;
    const int c0 = tid & 15;
    float sum = 0.f, sq = 0.f;
    #pragma unroll
    for (int i = 0; i < 19; ++i) {
        int c = c0 + 16 * i;
        if (c < OUT_) { float v = hlds[r * HSTR + c]; sum += v; sq += v * v; }
    }
    #pragma unroll
    for (int off = 8; off > 0; off >>= 1) {
        sum += __shfl_xor(sum, off);
        sq  += __shfl_xor(sq,  off);
    }
    const float mu  = sum * (1.0f / OUT_);
    const float var = sq * (1.0f / OUT_) - mu * mu;
    const float rs  = rsqrtf(var + EPS_);
    float* orow = out + (size_t)(blk * BM + r) * OUT_;
    #pragma unroll
    for (int i = 0; i < 19; ++i) {
        int c = c0 + 16 * i;
        if (c < OUT_) {
            float v = hlds[r * HSTR + c];
            orow[c] = (v - mu) * rs * gamma[c] + beta[c];
        }
    }
}

extern "C" void kernel_launch(void* const* d_in, const int* in_sizes, int n_in,
                              void* d_out, int out_size, void* d_ws, size_t ws_size,
                              hipStream_t stream) {
    const float* t1    = (const float*)d_in[0];
    const int*   wseq  = (const int*)d_in[1];   // word_seq (int32); d_in[2] mask unused
    const float* w_lin = (const float*)d_in[3];
    const float* b_lin = (const float*)d_in[4];
    const float* gamma = (const float*)d_in[5];
    const float* beta  = (const float*)d_in[6];
    float* out  = (float*)d_out;
    __bf16* wbf = (__bf16*)d_ws;                // 320*512*2 = 327680 B of scratch

    conv_w_kernel<<<(OUTP * D_) / 256, 256, 0, stream>>>(w_lin, wbf);
    enc_main<<<NBLK, 256, 0, stream>>>(t1, wseq, wbf, b_lin, gamma, beta, out);
    use_copy_kernel<<<(N_ * D_ / 4) / 256, 256, 0, stream>>>(t1, out + (size_t)M_TOTAL * OUT_);
}